// Round 1
// baseline (1104.639 us; speedup 1.0000x reference)
//
#include <hip/hip_runtime.h>
#include <cstdint>

// ---------------------------------------------------------------------------
// Block_7584912244953: graph transformer block on MI355X (gfx950)
// N=4096 nodes, M=16384 edges, E=512, H=8, D=64
// All GEMMs run as bf16 MFMA (threshold is 2% of absmax -> bf16-grade OK).
// GEMM convention: C(MxN) = A(MxK,row-major) @ B, with B supplied as
// Bt(NxK,row-major) so both LDS tiles are K-contiguous (ds_read_b128 frags).
// ---------------------------------------------------------------------------

typedef unsigned short u16;
typedef __bf16 bf16x8 __attribute__((ext_vector_type(8)));
typedef float f32x4 __attribute__((ext_vector_type(4)));

__device__ __forceinline__ u16 f2bf(float f) {
    unsigned u = __float_as_uint(f);
    return (u16)((u + 0x7fffu + ((u >> 16) & 1u)) >> 16);  // RNE
}
__device__ __forceinline__ float bf2f(u16 u) { return __uint_as_float(((unsigned)u) << 16); }
__device__ __forceinline__ float gelu_exact(float x) {
    return 0.5f * x * (1.0f + erff(x * 0.70710678118654752f));
}

// async global->LDS, 16B per lane. LDS dest is wave-uniform base + lane*16.
// Addr-space casts via uintptr_t match LLVM's flat<->local lowering
// (flat->local addrspacecast == truncate to low 32 bits).
__device__ __forceinline__ void gload_lds16(const u16* g, u16* l) {
    __builtin_amdgcn_global_load_lds(
        (const __attribute__((address_space(1))) unsigned int*)(uintptr_t)g,
        (__attribute__((address_space(3))) unsigned int*)(unsigned int)(uintptr_t)l,
        16, 0, 0);
}

// ---------------------------------------------------------------------------
// fp32 -> bf16 straight convert (adj, Wp1)
// ---------------------------------------------------------------------------
__global__ __launch_bounds__(256) void cvt_f32_bf16(const float* __restrict__ in,
                                                    u16* __restrict__ out, size_t n8) {
    size_t i = (size_t)blockIdx.x * 256 + threadIdx.x;
    size_t stride = (size_t)gridDim.x * 256;
    for (; i < n8; i += stride) {
        float4 a = ((const float4*)in)[i * 2];
        float4 b = ((const float4*)in)[i * 2 + 1];
        u16 r[8] = {f2bf(a.x), f2bf(a.y), f2bf(a.z), f2bf(a.w),
                    f2bf(b.x), f2bf(b.y), f2bf(b.z), f2bf(b.w)};
        ((uint4*)out)[i] = *(const uint4*)r;
    }
}

// ---------------------------------------------------------------------------
// fp32 (RxC) -> bf16 transposed (CxR).  Used for all weight matrices so the
// GEMM's Bt operand (NxK) is K-contiguous.
// ---------------------------------------------------------------------------
__global__ __launch_bounds__(256) void transpose_cvt(const float* __restrict__ in,
                                                     u16* __restrict__ out, int R, int C) {
    __shared__ float tile[32][33];
    int c0 = blockIdx.x * 32, r0 = blockIdx.y * 32;
    int tx = threadIdx.x & 31, ty = threadIdx.x >> 5;  // 32x8
#pragma unroll
    for (int i = 0; i < 4; ++i)
        tile[ty + i * 8][tx] = in[(size_t)(r0 + ty + i * 8) * C + c0 + tx];
    __syncthreads();
#pragma unroll
    for (int i = 0; i < 4; ++i)
        out[(size_t)(c0 + ty + i * 8) * R + r0 + tx] = f2bf(tile[tx][ty + i * 8]);
}

// ---------------------------------------------------------------------------
// RMSNorm (rows x 512) fp32 -> bf16
// ---------------------------------------------------------------------------
__global__ __launch_bounds__(256) void rmsnorm_bf16(const float* __restrict__ x,
                                                    const float* __restrict__ g,
                                                    u16* __restrict__ out) {
    int row = blockIdx.x, tid = threadIdx.x;
    const float* xr = x + (size_t)row * 512;
    float2 v = *(const float2*)(xr + tid * 2);
    float ss = v.x * v.x + v.y * v.y;
#pragma unroll
    for (int o = 32; o; o >>= 1) ss += __shfl_down(ss, o);
    __shared__ float red[4];
    if ((tid & 63) == 0) red[tid >> 6] = ss;
    __syncthreads();
    float tot = red[0] + red[1] + red[2] + red[3];
    float rs = rsqrtf(tot * (1.0f / 512.0f) + 1e-6f);
    unsigned pack = (unsigned)f2bf(v.x * rs * g[tid * 2]) |
                    ((unsigned)f2bf(v.y * rs * g[tid * 2 + 1]) << 16);
    ((unsigned*)out)[(size_t)row * 256 + tid] = pack;
}

// ---------------------------------------------------------------------------
// Core GEMM tile body: 128x128 tile, BK=32, 4 waves (2x2), each wave 64x64
// via 4x4 frags of v_mfma_f32_16x16x32_bf16 (m97 structure, ~900TF class).
// MODE: 0 = bf16 store, 1 = bf16 bias+gelu, 2 = f32 bias, 3 = f32 atomicAdd
// ---------------------------------------------------------------------------
template <int MODE>
__device__ __forceinline__ void gemm_tile_body(const u16* __restrict__ A,
                                               const u16* __restrict__ Bt,
                                               int N, int K, int k_begin, int k_end,
                                               int rowStart, int colStart,
                                               void* __restrict__ C,
                                               const float* __restrict__ bias) {
    __shared__ u16 Asm[128 * 32];
    __shared__ u16 Bsm[128 * 32];
    const int tid = threadIdx.x;
    const int wave = tid >> 6, lane = tid & 63;
    const int wr = wave >> 1, wc = wave & 1;

    f32x4 acc[4][4];
#pragma unroll
    for (int m = 0; m < 4; ++m)
#pragma unroll
        for (int n = 0; n < 4; ++n) acc[m][n] = f32x4{0.f, 0.f, 0.f, 0.f};

    // staging coords: 8KB tile = 8 x 1KB wave-calls (2 per wave)
    const int off0 = (wave * 2 + 0) * 1024 + lane * 16;
    const int off1 = (wave * 2 + 1) * 1024 + lane * 16;
    const int r0 = off0 >> 6, k0e = (off0 & 63) >> 1;
    const int r1 = off1 >> 6, k1e = (off1 & 63) >> 1;
    const size_t Arow0 = (size_t)(rowStart + r0) * K + k0e;
    const size_t Arow1 = (size_t)(rowStart + r1) * K + k1e;
    const size_t Brow0 = (size_t)(colStart + r0) * K + k0e;
    const size_t Brow1 = (size_t)(colStart + r1) * K + k1e;
    u16* As0 = &Asm[(wave * 2 + 0) * 512];
    u16* As1 = &Asm[(wave * 2 + 1) * 512];
    u16* Bs0 = &Bsm[(wave * 2 + 0) * 512];
    u16* Bs1 = &Bsm[(wave * 2 + 1) * 512];

    const int rsel = lane & 15, kselb = (lane >> 4) * 8;

    for (int kk = k_begin; kk < k_end; kk += 32) {
        gload_lds16(A + Arow0 + kk, As0);
        gload_lds16(A + Arow1 + kk, As1);
        gload_lds16(Bt + Brow0 + kk, Bs0);
        gload_lds16(Bt + Brow1 + kk, Bs1);
        __syncthreads();  // compiler drains vmcnt before s_barrier
        bf16x8 aF[4], bF[4];
#pragma unroll
        for (int m = 0; m < 4; ++m)
            aF[m] = *(const bf16x8*)&Asm[(wr * 64 + m * 16 + rsel) * 32 + kselb];
#pragma unroll
        for (int n = 0; n < 4; ++n)
            bF[n] = *(const bf16x8*)&Bsm[(wc * 64 + n * 16 + rsel) * 32 + kselb];
#pragma unroll
        for (int m = 0; m < 4; ++m)
#pragma unroll
            for (int n = 0; n < 4; ++n)
                acc[m][n] = __builtin_amdgcn_mfma_f32_16x16x32_bf16(aF[m], bF[n], acc[m][n], 0, 0, 0);
        __syncthreads();
    }

    // epilogue. C/D layout (measured m89/m91): col = lane&15, row = (lane>>4)*4 + j
    const int cq = (lane >> 4) * 4, cr = lane & 15;
#pragma unroll
    for (int m = 0; m < 4; ++m) {
#pragma unroll
        for (int n = 0; n < 4; ++n) {
            int col = colStart + wc * 64 + n * 16 + cr;
#pragma unroll
            for (int j = 0; j < 4; ++j) {
                int row = rowStart + wr * 64 + m * 16 + cq + j;
                float v = acc[m][n][j];
                if constexpr (MODE == 0) {
                    ((u16*)C)[(size_t)row * N + col] = f2bf(v);
                } else if constexpr (MODE == 1) {
                    v = gelu_exact(v + bias[col]);
                    ((u16*)C)[(size_t)row * N + col] = f2bf(v);
                } else if constexpr (MODE == 2) {
                    ((float*)C)[(size_t)row * N + col] = v + bias[col];
                } else {
                    atomicAdd(&((float*)C)[(size_t)row * N + col], v);
                }
            }
        }
    }
}

template <int MODE>
__global__ __launch_bounds__(256, 2) void gemm_bt(const u16* __restrict__ A,
                                                  const u16* __restrict__ Bt,
                                                  void* __restrict__ C,
                                                  const float* __restrict__ bias,
                                                  int N, int K, int kLen) {
    int kb = blockIdx.z * kLen;
    gemm_tile_body<MODE>(A, Bt, N, K, kb, kb + kLen, blockIdx.y * 128, blockIdx.x * 128, C, bias);
}

// 7 row-major node projections batched over z: C[z] = h @ W[z]  (A shared)
struct Batch7 { const u16* W[7]; u16* C[7]; };
__global__ __launch_bounds__(256, 2) void gemm_proj7(const u16* __restrict__ h, Batch7 b) {
    int z = blockIdx.z;
    gemm_tile_body<0>(h, b.W[z], 512, 512, 0, 512, blockIdx.y * 128, blockIdx.x * 128, b.C[z], nullptr);
}

// 5 transposed projections batched: C[z] (512 x Nz) = W[z]^T @ X[z]
struct Batch5 { const u16* A[5]; const u16* Bt[5]; u16* C[5]; int N[5]; };
__global__ __launch_bounds__(256, 2) void gemm_projT5(Batch5 b) {
    int z = blockIdx.z;
    int Nz = b.N[z];
    if (blockIdx.x * 128 >= Nz) return;  // whole block exits before any barrier
    gemm_tile_body<0>(b.A[z], b.Bt[z], Nz, 512, 0, 512, blockIdx.y * 128, blockIdx.x * 128, b.C[z], nullptr);
}

// ---------------------------------------------------------------------------
// Fused per-node SDPA (4 branches, HxH=8x8 softmax) + branch sum + RMSNorm*g2
// One block per node; wave w handles branch w. Outputs y (bf16) for the FFN.
// ---------------------------------------------------------------------------
__global__ __launch_bounds__(256) void sdpa_fused(
    const float* __restrict__ q0, const u16* __restrict__ k0, const u16* __restrict__ v0,   // hh
    const float* __restrict__ q1, const float* __restrict__ k1, const u16* __restrict__ v1, // ee
    const float* __restrict__ q2, const u16* __restrict__ k2, const u16* __restrict__ v2,   // eh
    const u16* __restrict__ q3, const float* __restrict__ k3, const u16* __restrict__ v3,   // he
    const float* __restrict__ g2, u16* __restrict__ y) {
    __shared__ float qb[4][8][65], kb[4][8][65], vb[4][8][65];  // +1 pad: kills 8-way bank conflicts
    __shared__ float aw[4][64];
    __shared__ float red[4];
    const int n = blockIdx.x, tid = threadIdx.x;
    const size_t base = (size_t)n * 512;
    const int e0 = tid * 2, hs = e0 >> 6, ds = e0 & 63;

    // stage q/k/v of all 4 branches to LDS as fp32 (2 elems/thread/array)
    {
        float2 f;
        unsigned u;
        f = *(const float2*)(q0 + base + e0); qb[0][hs][ds] = f.x; qb[0][hs][ds + 1] = f.y;
        u = *(const unsigned*)(k0 + base + e0); kb[0][hs][ds] = bf2f(u & 0xffffu); kb[0][hs][ds + 1] = bf2f(u >> 16);
        u = *(const unsigned*)(v0 + base + e0); vb[0][hs][ds] = bf2f(u & 0xffffu); vb[0][hs][ds + 1] = bf2f(u >> 16);
        f = *(const float2*)(q1 + base + e0); qb[1][hs][ds] = f.x; qb[1][hs][ds + 1] = f.y;
        f = *(const float2*)(k1 + base + e0); kb[1][hs][ds] = f.x; kb[1][hs][ds + 1] = f.y;
        u = *(const unsigned*)(v1 + base + e0); vb[1][hs][ds] = bf2f(u & 0xffffu); vb[1][hs][ds + 1] = bf2f(u >> 16);
        f = *(const float2*)(q2 + base + e0); qb[2][hs][ds] = f.x; qb[2][hs][ds + 1] = f.y;
        u = *(const unsigned*)(k2 + base + e0); kb[2][hs][ds] = bf2f(u & 0xffffu); kb[2][hs][ds + 1] = bf2f(u >> 16);
        u = *(const unsigned*)(v2 + base + e0); vb[2][hs][ds] = bf2f(u & 0xffffu); vb[2][hs][ds + 1] = bf2f(u >> 16);
        u = *(const unsigned*)(q3 + base + e0); qb[3][hs][ds] = bf2f(u & 0xffffu); qb[3][hs][ds + 1] = bf2f(u >> 16);
        f = *(const float2*)(k3 + base + e0); kb[3][hs][ds] = f.x; kb[3][hs][ds + 1] = f.y;
        u = *(const unsigned*)(v3 + base + e0); vb[3][hs][ds] = bf2f(u & 0xffffu); vb[3][hs][ds + 1] = bf2f(u >> 16);
    }
    __syncthreads();

    // s[b][h][g] : thread (b = wave, h = bits3..5, g = bits0..2)
    const int b = tid >> 6, h = (tid >> 3) & 7, g = tid & 7;
    float s = 0.f;
    const float* qr = &qb[b][h][0];
    const float* kr = &kb[b][g][0];
#pragma unroll
    for (int j = 0; j < 64; ++j) s += qr[j] * kr[j];
    s *= 0.125f;  // 1/sqrt(64)
    float mx = s;
#pragma unroll
    for (int o = 1; o < 8; o <<= 1) mx = fmaxf(mx, __shfl_xor(mx, o));
    float p = expf(s - mx);
    float sm = p;
#pragma unroll
    for (int o = 1; o < 8; o <<= 1) sm += __shfl_xor(sm, o);
    aw[b][(h << 3) | g] = p / sm;
    __syncthreads();

    // out[e] = sum_b sum_g a[b][h][g] * v[b][g][d]; 2 outputs per thread
    float o0 = 0.f, o1 = 0.f;
#pragma unroll
    for (int bb = 0; bb < 4; ++bb)
#pragma unroll
        for (int gg = 0; gg < 8; ++gg) {
            float a = aw[bb][(hs << 3) | gg];
            o0 += a * vb[bb][gg][ds];
            o1 += a * vb[bb][gg][ds + 1];
        }

    // fused RMSNorm over the 512-row + g2 scale -> bf16
    float ss = o0 * o0 + o1 * o1;
#pragma unroll
    for (int o = 32; o; o >>= 1) ss += __shfl_down(ss, o);
    if ((tid & 63) == 0) red[tid >> 6] = ss;
    __syncthreads();
    float tot = red[0] + red[1] + red[2] + red[3];
    float rs = rsqrtf(tot * (1.0f / 512.0f) + 1e-6f);
    unsigned pack = (unsigned)f2bf(o0 * rs * g2[e0]) | ((unsigned)f2bf(o1 * rs * g2[e0 + 1]) << 16);
    ((unsigned*)y)[(size_t)n * 256 + tid] = pack;
}

// ---------------------------------------------------------------------------
extern "C" void kernel_launch(void* const* d_in, const int* in_sizes, int n_in,
                              void* d_out, int out_size, void* d_ws, size_t ws_size,
                              hipStream_t stream) {
    (void)in_sizes; (void)n_in; (void)out_size; (void)ws_size;
    const int N = 4096, M = 16384, E = 512;

    const float* x_node = (const float*)d_in[0];
    const float* x_edge = (const float*)d_in[1];
    const float* adj    = (const float*)d_in[2];
    // weights 3..14: hh(q,k,v) ee(q,k,v) he(q,k,v) eh(q,k,v)
    const float* Wp1_he = (const float*)d_in[15];
    const float* Wp1_eh = (const float*)d_in[16];
    const float* Wp1_ee = (const float*)d_in[17];
    const float* g_n = (const float*)d_in[18];
    const float* g_e = (const float*)d_in[19];
    const float* g2  = (const float*)d_in[20];
    const float* Wf1 = (const float*)d_in[21];
    const float* bf1 = (const float*)d_in[22];
    const float* Wf2 = (const float*)d_in[23];
    const float* bf2 = (const float*)d_in[24];

    // ---- workspace bump allocator (~363 MB total) ----
    char* p = (char*)d_ws;
    auto alloc = [&](size_t b) { char* r = p; p += (b + 255) & ~(size_t)255; return r; };
    u16* h    = (u16*)alloc((size_t)N * E * 2);
    u16* e    = (u16*)alloc((size_t)M * E * 2);
    u16* Wt   = (u16*)alloc((size_t)12 * E * E * 2);      // W^T (NxK) for each E x E weight
    u16* Wf1T = (u16*)alloc((size_t)2048 * 512 * 2);
    u16* Wf2T = (u16*)alloc((size_t)512 * 2048 * 2);
    u16* adjb = (u16*)alloc((size_t)N * N * 2);
    u16* wp1b = (u16*)alloc((size_t)N * M * 2);           // shared: ee -> eh -> he sequenced
    u16* QhhT = (u16*)alloc((size_t)512 * N * 2);
    u16* QT   = (u16*)alloc((size_t)4 * 512 * M * 2);     // QeeT,KeeT,QehT,KheT
    u16* P7   = (u16*)alloc((size_t)7 * N * E * 2);       // Khh,Vhh,Vee,Keh,Veh,Qhe,Vhe
    float* F5 = (float*)alloc((size_t)5 * N * E * 4);     // AdjQ,PQee,PKee,PQeh,PKhe (splitK atomics)
    u16* y    = (u16*)alloc((size_t)N * E * 2);
    u16* t    = (u16*)alloc((size_t)N * 2048 * 2);

    const size_t WSZ = (size_t)E * E;   // 512*512
    const size_t NP = (size_t)N * E;    // 4096*512
    const size_t QTSZ = (size_t)512 * M;

    // ---- 1. weight conversions (transposed) ----
    for (int i = 0; i < 12; ++i)
        transpose_cvt<<<dim3(16, 16), 256, 0, stream>>>((const float*)d_in[3 + i], Wt + i * WSZ, 512, 512);
    transpose_cvt<<<dim3(64, 16), 256, 0, stream>>>(Wf1, Wf1T, 512, 2048);
    transpose_cvt<<<dim3(16, 64), 256, 0, stream>>>(Wf2, Wf2T, 2048, 512);
    cvt_f32_bf16<<<2048, 256, 0, stream>>>(adj, adjb, (size_t)N * N / 8);

    // ---- 2. RMSNorms ----
    rmsnorm_bf16<<<N, 256, 0, stream>>>(x_node, g_n, h);
    rmsnorm_bf16<<<M, 256, 0, stream>>>(x_edge, g_e, e);

    // ---- 3. projections ----
    // row-major (A=h): Khh,Vhh,Vee,Keh,Veh,Qhe,Vhe  (Wt index = input index - 3)
    Batch7 b7;
    const int wti7[7] = {1, 2, 5, 10, 11, 6, 8};
    for (int i = 0; i < 7; ++i) { b7.W[i] = Wt + wti7[i] * WSZ; b7.C[i] = P7 + i * NP; }
    gemm_proj7<<<dim3(4, 32, 7), 256, 0, stream>>>(h, b7);
    // transposed (C^T = W^T @ X): QhhT(h), QeeT/KeeT/QehT/KheT(e)
    Batch5 b5;
    b5.A[0] = Wt + 0 * WSZ; b5.Bt[0] = h; b5.C[0] = QhhT;        b5.N[0] = N;
    b5.A[1] = Wt + 3 * WSZ; b5.Bt[1] = e; b5.C[1] = QT + 0 * QTSZ; b5.N[1] = M;
    b5.A[2] = Wt + 4 * WSZ; b5.Bt[2] = e; b5.C[2] = QT + 1 * QTSZ; b5.N[2] = M;
    b5.A[3] = Wt + 9 * WSZ; b5.Bt[3] = e; b5.C[3] = QT + 2 * QTSZ; b5.N[3] = M;
    b5.A[4] = Wt + 7 * WSZ; b5.Bt[4] = e; b5.C[4] = QT + 3 * QTSZ; b5.N[4] = M;
    gemm_projT5<<<dim3(128, 4, 5), 256, 0, stream>>>(b5);

    // ---- 4. big projection GEMMs (splitK=4, fp32 atomic accumulate) ----
    hipMemsetAsync(F5, 0, (size_t)5 * NP * 4, stream);
    gemm_bt<3><<<dim3(4, 32, 4), 256, 0, stream>>>(adjb, QhhT, F5 + 0 * NP, nullptr, 512, 4096, 1024);
    cvt_f32_bf16<<<2048, 256, 0, stream>>>(Wp1_ee, wp1b, (size_t)N * M / 8);
    gemm_bt<3><<<dim3(4, 32, 4), 256, 0, stream>>>(wp1b, QT + 0 * QTSZ, F5 + 1 * NP, nullptr, 512, 16384, 4096);
    gemm_bt<3><<<dim3(4, 32, 4), 256, 0, stream>>>(wp1b, QT + 1 * QTSZ, F5 + 2 * NP, nullptr, 512, 16384, 4096);
    cvt_f32_bf16<<<2048, 256, 0, stream>>>(Wp1_eh, wp1b, (size_t)N * M / 8);
    gemm_bt<3><<<dim3(4, 32, 4), 256, 0, stream>>>(wp1b, QT + 2 * QTSZ, F5 + 3 * NP, nullptr, 512, 16384, 4096);
    cvt_f32_bf16<<<2048, 256, 0, stream>>>(Wp1_he, wp1b, (size_t)N * M / 8);
    gemm_bt<3><<<dim3(4, 32, 4), 256, 0, stream>>>(wp1b, QT + 3 * QTSZ, F5 + 4 * NP, nullptr, 512, 16384, 4096);

    // ---- 5. fused SDPA + branch-sum + RMSNorm(g2) -> y ----
    sdpa_fused<<<N, 256, 0, stream>>>(
        F5 + 0 * NP, P7 + 0 * NP, P7 + 1 * NP,   // hh: q=AdjQ, k=Khh, v=Vhh
        F5 + 1 * NP, F5 + 2 * NP, P7 + 2 * NP,   // ee: q=PQee, k=PKee, v=Vee
        F5 + 3 * NP, P7 + 3 * NP, P7 + 4 * NP,   // eh: q=PQeh, k=Keh, v=Veh
        P7 + 5 * NP, F5 + 4 * NP, P7 + 6 * NP,   // he: q=Qhe, k=PKhe, v=Vhe
        g2, y);

    // ---- 6. FFN ----
    gemm_bt<1><<<dim3(16, 32, 1), 256, 0, stream>>>(y, Wf1T, t, bf1, 2048, 512, 512);
    gemm_bt<2><<<dim3(4, 32, 1), 256, 0, stream>>>(t, Wf2T, d_out, bf2, 512, 2048, 2048);
}

// Round 2
// 671.524 us; speedup vs baseline: 1.6450x; 1.6450x over previous
//
#include <hip/hip_runtime.h>
#include <cstdint>

// ---------------------------------------------------------------------------
// Block_7584912244953 on MI355X (gfx950), restructured:
//   P_xx = Wp1_xx @ e   (3 big GEMMs, fp32 A fused-converted)   [was 4 + cvts]
//   Ah   = adj @ h      (fp32 A fused-converted)
//   12 batched N-row projections -> SDPA(8x8 heads) -> FFN
// GEMM convention: C(MxN) = A(MxK) @ Bt(NxK), K-contiguous LDS tiles.
// ---------------------------------------------------------------------------

typedef unsigned short u16;
typedef __bf16 bf16x8 __attribute__((ext_vector_type(8)));
typedef float f32x4 __attribute__((ext_vector_type(4)));

__device__ __forceinline__ u16 f2bf(float f) {
    unsigned u = __float_as_uint(f);
    return (u16)((u + 0x7fffu + ((u >> 16) & 1u)) >> 16);  // RNE
}
__device__ __forceinline__ float bf2f(u16 u) { return __uint_as_float(((unsigned)u) << 16); }
__device__ __forceinline__ float gelu_exact(float x) {
    return 0.5f * x * (1.0f + erff(x * 0.70710678118654752f));
}

__device__ __forceinline__ void gload_lds16(const u16* g, u16* l) {
    __builtin_amdgcn_global_load_lds(
        (const __attribute__((address_space(1))) unsigned int*)(uintptr_t)g,
        (__attribute__((address_space(3))) unsigned int*)(unsigned int)(uintptr_t)l,
        16, 0, 0);
}

// bijective XCD-aware block swizzle (requires gridDim product % 8 == 0)
__device__ __forceinline__ void swz_block(int& bx, int& by, int& bz) {
    const int nx = gridDim.x, ny = gridDim.y;
    const int nwg = nx * ny * gridDim.z;
    int lin = blockIdx.x + nx * (blockIdx.y + ny * blockIdx.z);
    const int chunk = nwg >> 3;
    lin = (lin & 7) * chunk + (lin >> 3);
    bx = lin % nx;
    lin /= nx;
    by = lin % ny;
    bz = lin / ny;
}

// ---------------------------------------------------------------------------
// fp32 -> bf16 straight convert (for the split-K fp32 accumulators)
// ---------------------------------------------------------------------------
__global__ __launch_bounds__(256) void cvt_f32_bf16(const float* __restrict__ in,
                                                    u16* __restrict__ out, size_t n8) {
    size_t i = (size_t)blockIdx.x * 256 + threadIdx.x;
    size_t stride = (size_t)gridDim.x * 256;
    for (; i < n8; i += stride) {
        float4 a = ((const float4*)in)[i * 2];
        float4 b = ((const float4*)in)[i * 2 + 1];
        u16 r[8] = {f2bf(a.x), f2bf(a.y), f2bf(a.z), f2bf(a.w),
                    f2bf(b.x), f2bf(b.y), f2bf(b.z), f2bf(b.w)};
        ((uint4*)out)[i] = *(const uint4*)r;
    }
}

// ---------------------------------------------------------------------------
// fp32 (RxC) -> bf16 transposed (CxR)
// ---------------------------------------------------------------------------
__global__ __launch_bounds__(256) void transpose_cvt(const float* __restrict__ in,
                                                     u16* __restrict__ out, int R, int C) {
    __shared__ float tile[32][33];
    int c0 = blockIdx.x * 32, r0 = blockIdx.y * 32;
    int tx = threadIdx.x & 31, ty = threadIdx.x >> 5;
#pragma unroll
    for (int i = 0; i < 4; ++i)
        tile[ty + i * 8][tx] = in[(size_t)(r0 + ty + i * 8) * C + c0 + tx];
    __syncthreads();
#pragma unroll
    for (int i = 0; i < 4; ++i)
        out[(size_t)(c0 + ty + i * 8) * R + r0 + tx] = f2bf(tile[tx][ty + i * 8]);
}

// batched version for the 12 ExE weights
struct W12 { const float* in[12]; u16* out[12]; };
__global__ __launch_bounds__(256) void transpose_cvt12(W12 w) {
    __shared__ float tile[32][33];
    const float* in = w.in[blockIdx.z];
    u16* out = w.out[blockIdx.z];
    int c0 = blockIdx.x * 32, r0 = blockIdx.y * 32;
    int tx = threadIdx.x & 31, ty = threadIdx.x >> 5;
#pragma unroll
    for (int i = 0; i < 4; ++i)
        tile[ty + i * 8][tx] = in[(size_t)(r0 + ty + i * 8) * 512 + c0 + tx];
    __syncthreads();
#pragma unroll
    for (int i = 0; i < 4; ++i)
        out[(size_t)(c0 + ty + i * 8) * 512 + r0 + tx] = f2bf(tile[tx][ty + i * 8]);
}

// bf16 (RxC) -> bf16 transposed (CxR)
__global__ __launch_bounds__(256) void transpose_u16(const u16* __restrict__ in,
                                                     u16* __restrict__ out, int R, int C) {
    __shared__ u16 tile[32][34];
    int c0 = blockIdx.x * 32, r0 = blockIdx.y * 32;
    int tx = threadIdx.x & 31, ty = threadIdx.x >> 5;
#pragma unroll
    for (int i = 0; i < 4; ++i)
        tile[ty + i * 8][tx] = in[(size_t)(r0 + ty + i * 8) * C + c0 + tx];
    __syncthreads();
#pragma unroll
    for (int i = 0; i < 4; ++i)
        out[(size_t)(c0 + ty + i * 8) * R + r0 + tx] = tile[tx][ty + i * 8];
}

// ---------------------------------------------------------------------------
// RMSNorm (rows x 512) fp32 -> bf16
// ---------------------------------------------------------------------------
__global__ __launch_bounds__(256) void rmsnorm_bf16(const float* __restrict__ x,
                                                    const float* __restrict__ g,
                                                    u16* __restrict__ out) {
    int row = blockIdx.x, tid = threadIdx.x;
    const float* xr = x + (size_t)row * 512;
    float2 v = *(const float2*)(xr + tid * 2);
    float ss = v.x * v.x + v.y * v.y;
#pragma unroll
    for (int o = 32; o; o >>= 1) ss += __shfl_down(ss, o);
    __shared__ float red[4];
    if ((tid & 63) == 0) red[tid >> 6] = ss;
    __syncthreads();
    float tot = red[0] + red[1] + red[2] + red[3];
    float rs = rsqrtf(tot * (1.0f / 512.0f) + 1e-6f);
    unsigned pack = (unsigned)f2bf(v.x * rs * g[tid * 2]) |
                    ((unsigned)f2bf(v.y * rs * g[tid * 2 + 1]) << 16);
    ((unsigned*)out)[(size_t)row * 256 + tid] = pack;
}

// ---------------------------------------------------------------------------
// bf16 GEMM tile body: 128x128 tile, BK=32, 4 waves (2x2), 4x4 frags of
// v_mfma_f32_16x16x32_bf16.  MODE: 0 bf16 store, 1 bf16 bias+gelu,
// 2 f32 bias store, 3 f32 atomicAdd (+bias if non-null)
// ---------------------------------------------------------------------------
template <int MODE>
__device__ __forceinline__ void gemm_tile_body(const u16* __restrict__ A,
                                               const u16* __restrict__ Bt,
                                               int N, int K, int k_begin, int k_end,
                                               int rowStart, int colStart,
                                               void* __restrict__ C,
                                               const float* __restrict__ bias) {
    __shared__ u16 Asm[128 * 32];
    __shared__ u16 Bsm[128 * 32];
    const int tid = threadIdx.x;
    const int wave = tid >> 6, lane = tid & 63;
    const int wr = wave >> 1, wc = wave & 1;

    f32x4 acc[4][4];
#pragma unroll
    for (int m = 0; m < 4; ++m)
#pragma unroll
        for (int n = 0; n < 4; ++n) acc[m][n] = f32x4{0.f, 0.f, 0.f, 0.f};

    const int off0 = (wave * 2 + 0) * 1024 + lane * 16;
    const int off1 = (wave * 2 + 1) * 1024 + lane * 16;
    const int r0 = off0 >> 6, k0e = (off0 & 63) >> 1;
    const int r1 = off1 >> 6, k1e = (off1 & 63) >> 1;
    const size_t Arow0 = (size_t)(rowStart + r0) * K + k0e;
    const size_t Arow1 = (size_t)(rowStart + r1) * K + k1e;
    const size_t Brow0 = (size_t)(colStart + r0) * K + k0e;
    const size_t Brow1 = (size_t)(colStart + r1) * K + k1e;
    u16* As0 = &Asm[(wave * 2 + 0) * 512];
    u16* As1 = &Asm[(wave * 2 + 1) * 512];
    u16* Bs0 = &Bsm[(wave * 2 + 0) * 512];
    u16* Bs1 = &Bsm[(wave * 2 + 1) * 512];

    const int rsel = lane & 15, kselb = (lane >> 4) * 8;

    for (int kk = k_begin; kk < k_end; kk += 32) {
        gload_lds16(A + Arow0 + kk, As0);
        gload_lds16(A + Arow1 + kk, As1);
        gload_lds16(Bt + Brow0 + kk, Bs0);
        gload_lds16(Bt + Brow1 + kk, Bs1);
        __syncthreads();
        bf16x8 aF[4], bF[4];
#pragma unroll
        for (int m = 0; m < 4; ++m)
            aF[m] = *(const bf16x8*)&Asm[(wr * 64 + m * 16 + rsel) * 32 + kselb];
#pragma unroll
        for (int n = 0; n < 4; ++n)
            bF[n] = *(const bf16x8*)&Bsm[(wc * 64 + n * 16 + rsel) * 32 + kselb];
#pragma unroll
        for (int m = 0; m < 4; ++m)
#pragma unroll
            for (int n = 0; n < 4; ++n)
                acc[m][n] = __builtin_amdgcn_mfma_f32_16x16x32_bf16(aF[m], bF[n], acc[m][n], 0, 0, 0);
        __syncthreads();
    }

    const int cq = (lane >> 4) * 4, cr = lane & 15;
#pragma unroll
    for (int m = 0; m < 4; ++m) {
#pragma unroll
        for (int n = 0; n < 4; ++n) {
            int col = colStart + wc * 64 + n * 16 + cr;
#pragma unroll
            for (int j = 0; j < 4; ++j) {
                int row = rowStart + wr * 64 + m * 16 + cq + j;
                float v = acc[m][n][j];
                if constexpr (MODE == 0) {
                    ((u16*)C)[(size_t)row * N + col] = f2bf(v);
                } else if constexpr (MODE == 1) {
                    v = gelu_exact(v + bias[col]);
                    ((u16*)C)[(size_t)row * N + col] = f2bf(v);
                } else if constexpr (MODE == 2) {
                    ((float*)C)[(size_t)row * N + col] = v + bias[col];
                } else {
                    if (bias) v += bias[col];
                    atomicAdd(&((float*)C)[(size_t)row * N + col], v);
                }
            }
        }
    }
}

template <int MODE>
__global__ __launch_bounds__(256, 2) void gemm_bt(const u16* __restrict__ A,
                                                  const u16* __restrict__ Bt,
                                                  void* __restrict__ C,
                                                  const float* __restrict__ bias,
                                                  int N, int K, int kLen) {
    int bx, by, bz;
    swz_block(bx, by, bz);
    const float* bb = (MODE == 3) ? ((bz == 0) ? bias : nullptr) : bias;
    int kb = bz * kLen;
    gemm_tile_body<MODE>(A, Bt, N, K, kb, kb + kLen, by * 128, bx * 128, C, bb);
}

// 12 batched N-row projections: C[z](4096x512) = A[z] @ W[z]^T
struct Small12 { const u16* A[12]; const u16* W[12]; u16* C[12]; };
__global__ __launch_bounds__(256, 2) void gemm_small12(Small12 s) {
    int bx, by, bz;
    swz_block(bx, by, bz);
    gemm_tile_body<0>(s.A[bz], s.W[bz], 512, 512, 0, 512, by * 128, bx * 128, s.C[bz], nullptr);
}

// ---------------------------------------------------------------------------
// Big GEMM with fp32 A (fused convert): C(4096x512) += A(4096xK fp32) @ Bt
// A reg-staged (dwordx4 -> cvt -> XOR-swizzled ds_write_b128); B global_load_lds.
// grid (4, 32, nMat*zPerMat), split-K atomic fp32.
// ---------------------------------------------------------------------------
struct Big3 { const float* A[3]; };
__global__ __launch_bounds__(256, 2) void gemm_f32a(Big3 ba, const u16* __restrict__ Bt,
                                                    float* __restrict__ C0, int K,
                                                    int zPerMat, int kLen) {
    __shared__ u16 Asm[128 * 32];
    __shared__ u16 Bsm[128 * 32];
    int bx, by, bz;
    swz_block(bx, by, bz);
    const int m = bz / zPerMat, ks = bz - m * zPerMat;
    const float* __restrict__ A = ba.A[m];
    float* __restrict__ C = C0 + (size_t)m * (4096 * 512);
    const int rowStart = by * 128, colStart = bx * 128;
    const int k0 = ks * kLen, kEnd = k0 + kLen;

    const int tid = threadIdx.x;
    const int wave = tid >> 6, lane = tid & 63;
    const int wr = wave >> 1, wc = wave & 1;

    f32x4 acc[4][4];
#pragma unroll
    for (int mm = 0; mm < 4; ++mm)
#pragma unroll
        for (int n = 0; n < 4; ++n) acc[mm][n] = f32x4{0.f, 0.f, 0.f, 0.f};

    // A staging: thread t handles row t>>1, half (t&1)*16 of the 32-k slice
    const int r = tid >> 1, half = tid & 1;
    const float4* Ap4 = (const float4*)(A + (size_t)(rowStart + r) * K + half * 16);
    const int sw = (r & 7) << 4;  // XOR swizzle: spreads 64B-stride rows across banks
    u16* aw0 = (u16*)((char*)Asm + (((r * 64 + half * 32) ^ sw)));
    u16* aw1 = (u16*)((char*)Asm + (((r * 64 + half * 32 + 16) ^ sw)));

    // B staging (bf16, global_load_lds): 8KB = 8 x 1KB wave-calls
    const int off0 = (wave * 2 + 0) * 1024 + lane * 16;
    const int off1 = (wave * 2 + 1) * 1024 + lane * 16;
    const int br0 = off0 >> 6, bk0 = (off0 & 63) >> 1;
    const int br1 = off1 >> 6, bk1 = (off1 & 63) >> 1;
    const u16* Bp0 = Bt + (size_t)(colStart + br0) * K + bk0;
    const u16* Bp1 = Bt + (size_t)(colStart + br1) * K + bk1;
    u16* Bs0 = &Bsm[(wave * 2 + 0) * 512];
    u16* Bs1 = &Bsm[(wave * 2 + 1) * 512];

    const int rsel = lane & 15, ksel = lane >> 4;

    float4 a0, a1, a2, a3;
    {
        const float4* p = Ap4 + (k0 >> 2);
        a0 = p[0]; a1 = p[1]; a2 = p[2]; a3 = p[3];
    }
    for (int kk = k0; kk < kEnd; kk += 32) {
        gload_lds16(Bp0 + kk, Bs0);
        gload_lds16(Bp1 + kk, Bs1);
        bf16x8 c0, c1;
        c0[0] = (__bf16)a0.x; c0[1] = (__bf16)a0.y; c0[2] = (__bf16)a0.z; c0[3] = (__bf16)a0.w;
        c0[4] = (__bf16)a1.x; c0[5] = (__bf16)a1.y; c0[6] = (__bf16)a1.z; c0[7] = (__bf16)a1.w;
        c1[0] = (__bf16)a2.x; c1[1] = (__bf16)a2.y; c1[2] = (__bf16)a2.z; c1[3] = (__bf16)a2.w;
        c1[4] = (__bf16)a3.x; c1[5] = (__bf16)a3.y; c1[6] = (__bf16)a3.z; c1[7] = (__bf16)a3.w;
        *(bf16x8*)aw0 = c0;
        *(bf16x8*)aw1 = c1;
        if (kk + 32 < kEnd) {  // prefetch next A slice into regs
            const float4* p = Ap4 + ((kk + 32) >> 2);
            a0 = p[0]; a1 = p[1]; a2 = p[2]; a3 = p[3];
        }
        __syncthreads();
        bf16x8 aF[4], bF[4];
#pragma unroll
        for (int mm = 0; mm < 4; ++mm) {
            int R = wr * 64 + mm * 16 + rsel;
            aF[mm] = *(const bf16x8*)((char*)Asm + ((R * 64 + ksel * 16) ^ ((R & 7) << 4)));
        }
#pragma unroll
        for (int n = 0; n < 4; ++n)
            bF[n] = *(const bf16x8*)&Bsm[(wc * 64 + n * 16 + rsel) * 32 + ksel * 8];
#pragma unroll
        for (int mm = 0; mm < 4; ++mm)
#pragma unroll
            for (int n = 0; n < 4; ++n)
                acc[mm][n] = __builtin_amdgcn_mfma_f32_16x16x32_bf16(aF[mm], bF[n], acc[mm][n], 0, 0, 0);
        __syncthreads();
    }

    const int cq = (lane >> 4) * 4, cr = lane & 15;
#pragma unroll
    for (int mm = 0; mm < 4; ++mm)
#pragma unroll
        for (int n = 0; n < 4; ++n) {
            int col = colStart + wc * 64 + n * 16 + cr;
#pragma unroll
            for (int j = 0; j < 4; ++j) {
                int row = rowStart + wr * 64 + mm * 16 + cq + j;
                atomicAdd(&C[(size_t)row * 512 + col], acc[mm][n][j]);
            }
        }
}

// ---------------------------------------------------------------------------
// Fused per-node SDPA (4 branches, 8x8 softmax) + branch sum + RMSNorm*g2
// All 12 q/k/v inputs bf16.  p order: [Qhh,Khh,Vhh,Qee,Kee,Vee,Qeh,Keh,Veh,Qhe,Khe,Vhe]
// ---------------------------------------------------------------------------
struct SP12 { const u16* p[12]; };
__global__ __launch_bounds__(256) void sdpa_fused(SP12 sp, const float* __restrict__ g2,
                                                  u16* __restrict__ y) {
    __shared__ float qb[4][8][65], kb[4][8][65], vb[4][8][65];
    __shared__ float aw[4][64];
    __shared__ float red[4];
    const int n = blockIdx.x, tid = threadIdx.x;
    const size_t base = (size_t)n * 512;
    const int e0 = tid * 2, hs = e0 >> 6, ds = e0 & 63;

#pragma unroll
    for (int br = 0; br < 4; ++br) {
        unsigned u;
        u = *(const unsigned*)(sp.p[br * 3 + 0] + base + e0);
        qb[br][hs][ds] = bf2f(u & 0xffffu); qb[br][hs][ds + 1] = bf2f(u >> 16);
        u = *(const unsigned*)(sp.p[br * 3 + 1] + base + e0);
        kb[br][hs][ds] = bf2f(u & 0xffffu); kb[br][hs][ds + 1] = bf2f(u >> 16);
        u = *(const unsigned*)(sp.p[br * 3 + 2] + base + e0);
        vb[br][hs][ds] = bf2f(u & 0xffffu); vb[br][hs][ds + 1] = bf2f(u >> 16);
    }
    __syncthreads();

    const int b = tid >> 6, h = (tid >> 3) & 7, g = tid & 7;
    float s = 0.f;
    const float* qr = &qb[b][h][0];
    const float* kr = &kb[b][g][0];
#pragma unroll
    for (int j = 0; j < 64; ++j) s += qr[j] * kr[j];
    s *= 0.125f;
    float mx = s;
#pragma unroll
    for (int o = 1; o < 8; o <<= 1) mx = fmaxf(mx, __shfl_xor(mx, o));
    float p = expf(s - mx);
    float sm = p;
#pragma unroll
    for (int o = 1; o < 8; o <<= 1) sm += __shfl_xor(sm, o);
    aw[b][(h << 3) | g] = p / sm;
    __syncthreads();

    float o0 = 0.f, o1 = 0.f;
#pragma unroll
    for (int bb = 0; bb < 4; ++bb)
#pragma unroll
        for (int gg = 0; gg < 8; ++gg) {
            float a = aw[bb][(hs << 3) | gg];
            o0 += a * vb[bb][gg][ds];
            o1 += a * vb[bb][gg][ds + 1];
        }

    float ss = o0 * o0 + o1 * o1;
#pragma unroll
    for (int o = 32; o; o >>= 1) ss += __shfl_down(ss, o);
    if ((tid & 63) == 0) red[tid >> 6] = ss;
    __syncthreads();
    float tot = red[0] + red[1] + red[2] + red[3];
    float rs = rsqrtf(tot * (1.0f / 512.0f) + 1e-6f);
    unsigned pack = (unsigned)f2bf(o0 * rs * g2[e0]) | ((unsigned)f2bf(o1 * rs * g2[e0 + 1]) << 16);
    ((unsigned*)y)[(size_t)n * 256 + tid] = pack;
}

// ---------------------------------------------------------------------------
extern "C" void kernel_launch(void* const* d_in, const int* in_sizes, int n_in,
                              void* d_out, int out_size, void* d_ws, size_t ws_size,
                              hipStream_t stream) {
    (void)in_sizes; (void)n_in; (void)out_size; (void)ws_size;
    const int N = 4096, M = 16384, E = 512;

    const float* x_node = (const float*)d_in[0];
    const float* x_edge = (const float*)d_in[1];
    const float* adj    = (const float*)d_in[2];
    const float* Wp1_he = (const float*)d_in[15];
    const float* Wp1_eh = (const float*)d_in[16];
    const float* Wp1_ee = (const float*)d_in[17];
    const float* g_n = (const float*)d_in[18];
    const float* g_e = (const float*)d_in[19];
    const float* g2  = (const float*)d_in[20];
    const float* Wf1 = (const float*)d_in[21];
    const float* bf1 = (const float*)d_in[22];
    const float* Wf2 = (const float*)d_in[23];
    const float* bf2 = (const float*)d_in[24];

    // ---- workspace ----
    char* p = (char*)d_ws;
    auto alloc = [&](size_t b) { char* r = p; p += (b + 255) & ~(size_t)255; return r; };
    const size_t NP = (size_t)N * E;
    const size_t WSZ = (size_t)E * E;
    u16* h    = (u16*)alloc(NP * 2);
    u16* hT   = (u16*)alloc(NP * 2);
    u16* e    = (u16*)alloc((size_t)M * E * 2);
    u16* eT   = (u16*)alloc((size_t)M * E * 2);
    u16* Wt   = (u16*)alloc(12 * WSZ * 2);
    u16* Wf1T = (u16*)alloc((size_t)2048 * 512 * 2);
    u16* Wf2T = (u16*)alloc((size_t)512 * 2048 * 2);
    float* F4 = (float*)alloc(4 * NP * 4);      // Pee, Peh, Phe, Ah (fp32 split-K acc)
    u16* P4b  = (u16*)alloc(4 * NP * 2);        // bf16 versions
    u16* S12  = (u16*)alloc(12 * NP * 2);       // Q/K/V per branch
    u16* y    = (u16*)alloc(NP * 2);
    u16* t    = (u16*)alloc((size_t)N * 2048 * 2);

    // ---- 1. weight transposes ----
    W12 w12;
    for (int i = 0; i < 12; ++i) { w12.in[i] = (const float*)d_in[3 + i]; w12.out[i] = Wt + i * WSZ; }
    transpose_cvt12<<<dim3(16, 16, 12), 256, 0, stream>>>(w12);
    transpose_cvt<<<dim3(64, 16), 256, 0, stream>>>(Wf1, Wf1T, 512, 2048);
    transpose_cvt<<<dim3(16, 64), 256, 0, stream>>>(Wf2, Wf2T, 2048, 512);

    // ---- 2. RMSNorms + transposes ----
    rmsnorm_bf16<<<N, 256, 0, stream>>>(x_node, g_n, h);
    rmsnorm_bf16<<<M, 256, 0, stream>>>(x_edge, g_e, e);
    transpose_u16<<<dim3(16, 128), 256, 0, stream>>>(h, hT, N, 512);
    transpose_u16<<<dim3(16, 512), 256, 0, stream>>>(e, eT, M, 512);

    // ---- 3. big GEMMs: P = Wp1 @ e (3 batched), Ah = adj @ h ----
    hipMemsetAsync(F4, 0, 4 * NP * 4, stream);
    Big3 bp; bp.A[0] = Wp1_ee; bp.A[1] = Wp1_eh; bp.A[2] = Wp1_he;
    gemm_f32a<<<dim3(4, 32, 12), 256, 0, stream>>>(bp, eT, F4, M, 4, 4096);
    Big3 badj; badj.A[0] = adj; badj.A[1] = adj; badj.A[2] = adj;
    gemm_f32a<<<dim3(4, 32, 2), 256, 0, stream>>>(badj, hT, F4 + 3 * NP, N, 2, 2048);
    cvt_f32_bf16<<<2048, 256, 0, stream>>>(F4, P4b, 4 * NP / 8);
    const u16* Peeb = P4b + 0 * NP;
    const u16* Pehb = P4b + 1 * NP;
    const u16* Pheb = P4b + 2 * NP;
    const u16* Ahb  = P4b + 3 * NP;

    // ---- 4. 12 batched projections ----
    // S order: Qhh,Khh,Vhh, Qee,Kee,Vee, Qeh,Keh,Veh, Qhe,Khe,Vhe
    // Wt idx:  0=Wq_hh 1=Wk_hh 2=Wv_hh 3=Wq_ee 4=Wk_ee 5=Wv_ee
    //          6=Wq_he 7=Wk_he 8=Wv_he 9=Wq_eh 10=Wk_eh 11=Wv_eh
    Small12 sb;
    const u16* aList[12] = {Ahb, h, h, Peeb, Peeb, h, Pehb, h, h, h, Pheb, h};
    const int wList[12]  = {0, 1, 2, 3, 4, 5, 9, 10, 11, 6, 7, 8};
    for (int i = 0; i < 12; ++i) {
        sb.A[i] = aList[i];
        sb.W[i] = Wt + wList[i] * WSZ;
        sb.C[i] = S12 + i * NP;
    }
    gemm_small12<<<dim3(4, 32, 12), 256, 0, stream>>>(sb);

    // ---- 5. SDPA + sum + RMSNorm ----
    SP12 sp;
    for (int i = 0; i < 12; ++i) sp.p[i] = S12 + i * NP;
    sdpa_fused<<<N, 256, 0, stream>>>(sp, g2, y);

    // ---- 6. FFN ----
    gemm_bt<1><<<dim3(16, 32, 1), 256, 0, stream>>>(y, Wf1T, t, bf1, 2048, 512, 512);
    hipMemsetAsync(d_out, 0, NP * 4, stream);
    gemm_bt<3><<<dim3(4, 32, 2), 256, 0, stream>>>(t, Wf2T, d_out, bf2, 512, 2048, 1024);
}

// Round 3
// 638.468 us; speedup vs baseline: 1.7301x; 1.0518x over previous
//
#include <hip/hip_runtime.h>
#include <cstdint>

// ---------------------------------------------------------------------------
// Block_7584912244953 on MI355X (gfx950).
//   P_xx = Wp1_xx @ e (3 big GEMMs, fp32 A fused-converted, split-K atomics)
//   Ah   = adj @ h    (sparse ballot-scan gather, deg~8)
//   12 batched projections -> per-node 8x8 SDPA -> FFN
// All bf16 GEMM operands live in a "swz" layout: element (row,k) stored at
// k ^ ((row&3)<<3)  (XOR of the 16B slot within each 32-k window). This makes
// MFMA fragment ds_read_b128 bank-conflict-free while keeping
// global_load_lds destinations linear (guide rule #21).
// ---------------------------------------------------------------------------

typedef unsigned short u16;
typedef __bf16 bf16x8 __attribute__((ext_vector_type(8)));
typedef float f32x4 __attribute__((ext_vector_type(4)));

__device__ __forceinline__ u16 f2bf(float f) {
    unsigned u = __float_as_uint(f);
    return (u16)((u + 0x7fffu + ((u >> 16) & 1u)) >> 16);  // RNE
}
__device__ __forceinline__ float bf2f(u16 u) { return __uint_as_float(((unsigned)u) << 16); }
__device__ __forceinline__ float gelu_exact(float x) {
    return 0.5f * x * (1.0f + erff(x * 0.70710678118654752f));
}

__device__ __forceinline__ void gload_lds16(const u16* g, u16* l) {
    __builtin_amdgcn_global_load_lds(
        (const __attribute__((address_space(1))) unsigned int*)(uintptr_t)g,
        (__attribute__((address_space(3))) unsigned int*)(unsigned int)(uintptr_t)l,
        16, 0, 0);
}

// bijective XCD-aware block swizzle (gridDim product % 8 == 0)
__device__ __forceinline__ void swz_block(int& bx, int& by, int& bz) {
    const int nx = gridDim.x, ny = gridDim.y;
    const int nwg = nx * ny * gridDim.z;
    int lin = blockIdx.x + nx * (blockIdx.y + ny * blockIdx.z);
    const int chunk = nwg >> 3;
    lin = (lin & 7) * chunk + (lin >> 3);
    bx = lin % nx;
    lin /= nx;
    by = lin % ny;
    bz = lin / ny;
}

// ---------------------------------------------------------------------------
// fp32 -> bf16 convert; SWZ=true emits swz layout (rows of 512 elems = 64
// 8-elem chunks; chunk' = chunk ^ (row&3)).
// ---------------------------------------------------------------------------
template <bool SWZ>
__global__ __launch_bounds__(256) void cvt_f32_bf16(const float* __restrict__ in,
                                                    u16* __restrict__ out, size_t n8) {
    size_t i = (size_t)blockIdx.x * 256 + threadIdx.x;
    size_t stride = (size_t)gridDim.x * 256;
    for (; i < n8; i += stride) {
        float4 a = ((const float4*)in)[i * 2];
        float4 b = ((const float4*)in)[i * 2 + 1];
        u16 r[8] = {f2bf(a.x), f2bf(a.y), f2bf(a.z), f2bf(a.w),
                    f2bf(b.x), f2bf(b.y), f2bf(b.z), f2bf(b.w)};
        size_t o = i;
        if constexpr (SWZ) o = (i & ~(size_t)63) | ((i & 63) ^ ((i >> 6) & 3));
        ((uint4*)out)[o] = *(const uint4*)r;
    }
}

// ---------------------------------------------------------------------------
// fp32 (RxC) -> bf16 transposed (CxR), swz output layout
// ---------------------------------------------------------------------------
__global__ __launch_bounds__(256) void transpose_cvt(const float* __restrict__ in,
                                                     u16* __restrict__ out, int R, int C) {
    __shared__ float tile[32][33];
    int c0 = blockIdx.x * 32, r0 = blockIdx.y * 32;
    int tx = threadIdx.x & 31, ty = threadIdx.x >> 5;
#pragma unroll
    for (int i = 0; i < 4; ++i)
        tile[ty + i * 8][tx] = in[(size_t)(r0 + ty + i * 8) * C + c0 + tx];
    __syncthreads();
#pragma unroll
    for (int i = 0; i < 4; ++i) {
        int orow = c0 + ty + i * 8;
        out[(size_t)orow * R + ((r0 + tx) ^ ((orow & 3) << 3))] = f2bf(tile[tx][ty + i * 8]);
    }
}

struct W12 { const float* in[12]; u16* out[12]; };
__global__ __launch_bounds__(256) void transpose_cvt12(W12 w) {
    __shared__ float tile[32][33];
    const float* in = w.in[blockIdx.z];
    u16* out = w.out[blockIdx.z];
    int c0 = blockIdx.x * 32, r0 = blockIdx.y * 32;
    int tx = threadIdx.x & 31, ty = threadIdx.x >> 5;
#pragma unroll
    for (int i = 0; i < 4; ++i)
        tile[ty + i * 8][tx] = in[(size_t)(r0 + ty + i * 8) * 512 + c0 + tx];
    __syncthreads();
#pragma unroll
    for (int i = 0; i < 4; ++i) {
        int orow = c0 + ty + i * 8;
        out[(size_t)orow * 512 + ((r0 + tx) ^ ((orow & 3) << 3))] = f2bf(tile[tx][ty + i * 8]);
    }
}

// bf16 (RxC, plain) -> bf16 transposed (CxR, swz)
__global__ __launch_bounds__(256) void transpose_u16(const u16* __restrict__ in,
                                                     u16* __restrict__ out, int R, int C) {
    __shared__ u16 tile[32][34];
    int c0 = blockIdx.x * 32, r0 = blockIdx.y * 32;
    int tx = threadIdx.x & 31, ty = threadIdx.x >> 5;
#pragma unroll
    for (int i = 0; i < 4; ++i)
        tile[ty + i * 8][tx] = in[(size_t)(r0 + ty + i * 8) * C + c0 + tx];
    __syncthreads();
#pragma unroll
    for (int i = 0; i < 4; ++i) {
        int orow = c0 + ty + i * 8;
        out[(size_t)orow * R + ((r0 + tx) ^ ((orow & 3) << 3))] = tile[tx][ty + i * 8];
    }
}

// ---------------------------------------------------------------------------
// RMSNorm (rows x 512) fp32 -> bf16; SWZ selects output layout
// ---------------------------------------------------------------------------
template <bool SWZ>
__global__ __launch_bounds__(256) void rmsnorm_bf16(const float* __restrict__ x,
                                                    const float* __restrict__ g,
                                                    u16* __restrict__ out) {
    int row = blockIdx.x, tid = threadIdx.x;
    const float* xr = x + (size_t)row * 512;
    float2 v = *(const float2*)(xr + tid * 2);
    float ss = v.x * v.x + v.y * v.y;
#pragma unroll
    for (int o = 32; o; o >>= 1) ss += __shfl_down(ss, o);
    __shared__ float red[4];
    if ((tid & 63) == 0) red[tid >> 6] = ss;
    __syncthreads();
    float tot = red[0] + red[1] + red[2] + red[3];
    float rs = rsqrtf(tot * (1.0f / 512.0f) + 1e-6f);
    unsigned pack = (unsigned)f2bf(v.x * rs * g[tid * 2]) |
                    ((unsigned)f2bf(v.y * rs * g[tid * 2 + 1]) << 16);
    int o32 = SWZ ? (tid ^ ((row & 3) << 2)) : tid;  // u32-index swizzle = u16 <<3
    ((unsigned*)out)[(size_t)row * 256 + o32] = pack;
}

// ---------------------------------------------------------------------------
// Sparse Ah = adj @ h (adj ~0.2% dense binary). One wave per node.
// h and out are swz bf16.
// ---------------------------------------------------------------------------
__global__ __launch_bounds__(256) void adj_spmm(const float* __restrict__ adj,
                                                const u16* __restrict__ h,
                                                u16* __restrict__ out) {
    const int wave = threadIdx.x >> 6, lane = threadIdx.x & 63;
    const int n = blockIdx.x * 4 + wave;
    const float* arow = adj + (size_t)n * 4096;
    float acc[8] = {0.f, 0.f, 0.f, 0.f, 0.f, 0.f, 0.f, 0.f};
    for (int j = 0; j < 64; ++j) {
        float v = arow[j * 64 + lane];
        unsigned long long mask = __ballot(v != 0.0f);
        while (mask) {
            int bit = __ffsll((long long)mask) - 1;
            mask &= mask - 1;
            int m = j * 64 + bit;
            float w = __shfl(v, bit);
            int cs = (lane & ~3) | ((lane & 3) ^ (m & 3));
            uint4 q = *(const uint4*)(h + (size_t)m * 512 + cs * 8);
            const u16* qu = (const u16*)&q;
#pragma unroll
            for (int t = 0; t < 8; ++t) acc[t] += w * bf2f(qu[t]);
        }
    }
    int co = (lane & ~3) | ((lane & 3) ^ (n & 3));
    u16 r[8];
#pragma unroll
    for (int t = 0; t < 8; ++t) r[t] = f2bf(acc[t]);
    *(uint4*)(out + (size_t)n * 512 + co * 8) = *(const uint4*)r;
}

// ---------------------------------------------------------------------------
// bf16 GEMM tile body: 128x128 tile, BK=32, 4 waves (2x2), 4x4 frags of
// v_mfma_f32_16x16x32_bf16. A and Bt are swz-layout bf16.
// MODE: 0 bf16 plain store, 1 bf16 bias+gelu swz store, 3 f32 atomicAdd(+bias)
// ---------------------------------------------------------------------------
template <int MODE>
__device__ __forceinline__ void gemm_tile_body(const u16* __restrict__ A,
                                               const u16* __restrict__ Bt,
                                               int N, int K, int k_begin, int k_end,
                                               int rowStart, int colStart,
                                               void* __restrict__ C,
                                               const float* __restrict__ bias) {
    __shared__ u16 Asm[128 * 32];
    __shared__ u16 Bsm[128 * 32];
    const int tid = threadIdx.x;
    const int wave = tid >> 6, lane = tid & 63;
    const int wr = wave >> 1, wc = wave & 1;

    f32x4 acc[4][4];
#pragma unroll
    for (int m = 0; m < 4; ++m)
#pragma unroll
        for (int n = 0; n < 4; ++n) acc[m][n] = f32x4{0.f, 0.f, 0.f, 0.f};

    const int off0 = (wave * 2 + 0) * 1024 + lane * 16;
    const int off1 = (wave * 2 + 1) * 1024 + lane * 16;
    const int r0 = off0 >> 6, k0e = (off0 & 63) >> 1;
    const int r1 = off1 >> 6, k1e = (off1 & 63) >> 1;
    const size_t Arow0 = (size_t)(rowStart + r0) * K + k0e;
    const size_t Arow1 = (size_t)(rowStart + r1) * K + k1e;
    const size_t Brow0 = (size_t)(colStart + r0) * K + k0e;
    const size_t Brow1 = (size_t)(colStart + r1) * K + k1e;
    u16* As0 = &Asm[(wave * 2 + 0) * 512];
    u16* As1 = &Asm[(wave * 2 + 1) * 512];
    u16* Bs0 = &Bsm[(wave * 2 + 0) * 512];
    u16* Bs1 = &Bsm[(wave * 2 + 1) * 512];

    const int rsel = lane & 15, ksel = lane >> 4;
    const int fsw = ((ksel ^ (rsel & 3)) << 3);  // swz fragment slot

    for (int kk = k_begin; kk < k_end; kk += 32) {
        gload_lds16(A + Arow0 + kk, As0);
        gload_lds16(A + Arow1 + kk, As1);
        gload_lds16(Bt + Brow0 + kk, Bs0);
        gload_lds16(Bt + Brow1 + kk, Bs1);
        __syncthreads();
        bf16x8 aF[4], bF[4];
#pragma unroll
        for (int m = 0; m < 4; ++m)
            aF[m] = *(const bf16x8*)&Asm[(wr * 64 + m * 16 + rsel) * 32 + fsw];
#pragma unroll
        for (int n = 0; n < 4; ++n)
            bF[n] = *(const bf16x8*)&Bsm[(wc * 64 + n * 16 + rsel) * 32 + fsw];
#pragma unroll
        for (int m = 0; m < 4; ++m)
#pragma unroll
            for (int n = 0; n < 4; ++n)
                acc[m][n] = __builtin_amdgcn_mfma_f32_16x16x32_bf16(aF[m], bF[n], acc[m][n], 0, 0, 0);
        __syncthreads();
    }

    const int cq = (lane >> 4) * 4, cr = lane & 15;
#pragma unroll
    for (int m = 0; m < 4; ++m) {
#pragma unroll
        for (int n = 0; n < 4; ++n) {
            int col = colStart + wc * 64 + n * 16 + cr;
#pragma unroll
            for (int j = 0; j < 4; ++j) {
                int row = rowStart + wr * 64 + m * 16 + cq + j;
                float v = acc[m][n][j];
                if constexpr (MODE == 0) {
                    ((u16*)C)[(size_t)row * N + col] = f2bf(v);
                } else if constexpr (MODE == 1) {
                    v = gelu_exact(v + bias[col]);
                    ((u16*)C)[(size_t)row * N + (col ^ ((row & 3) << 3))] = f2bf(v);
                } else {
                    if (bias) v += bias[col];
                    atomicAdd(&((float*)C)[(size_t)row * N + col], v);
                }
            }
        }
    }
}

template <int MODE>
__global__ __launch_bounds__(256, 2) void gemm_bt(const u16* __restrict__ A,
                                                  const u16* __restrict__ Bt,
                                                  void* __restrict__ C,
                                                  const float* __restrict__ bias,
                                                  int N, int K, int kLen) {
    int bx, by, bz;
    swz_block(bx, by, bz);
    const float* bb = (MODE == 3) ? ((bz == 0) ? bias : nullptr) : bias;
    int kb = bz * kLen;
    gemm_tile_body<MODE>(A, Bt, N, K, kb, kb + kLen, by * 128, bx * 128, C, bb);
}

// 12 batched projections: C[z](4096x512) = A[z] @ W[z]^T (plain bf16 out)
struct Small12 { const u16* A[12]; const u16* W[12]; u16* C[12]; };
__global__ __launch_bounds__(256, 2) void gemm_small12(Small12 s) {
    int bx, by, bz;
    swz_block(bx, by, bz);
    gemm_tile_body<0>(s.A[bz], s.W[bz], 512, 512, 0, 512, by * 128, bx * 128, s.C[bz], nullptr);
}

// ---------------------------------------------------------------------------
// Big GEMM, fp32 A fused-converted: C(4096x512) += A(4096xK fp32) @ Bt(swz)
// ---------------------------------------------------------------------------
struct Big3 { const float* A[3]; };
__global__ __launch_bounds__(256, 2) void gemm_f32a(Big3 ba, const u16* __restrict__ Bt,
                                                    float* __restrict__ C0, int K,
                                                    int zPerMat, int kLen) {
    __shared__ u16 Asm[128 * 32];
    __shared__ u16 Bsm[128 * 32];
    int bx, by, bz;
    swz_block(bx, by, bz);
    const int m = bz / zPerMat, ks = bz - m * zPerMat;
    const float* __restrict__ A = ba.A[m];
    float* __restrict__ C = C0 + (size_t)m * (4096 * 512);
    const int rowStart = by * 128, colStart = bx * 128;
    const int k0 = ks * kLen, kEnd = k0 + kLen;

    const int tid = threadIdx.x;
    const int wave = tid >> 6, lane = tid & 63;
    const int wr = wave >> 1, wc = wave & 1;

    f32x4 acc[4][4];
#pragma unroll
    for (int mm = 0; mm < 4; ++mm)
#pragma unroll
        for (int n = 0; n < 4; ++n) acc[mm][n] = f32x4{0.f, 0.f, 0.f, 0.f};

    // A staging: thread t: row t>>1, half (t&1)*16 of the 32-k slice
    const int r = tid >> 1, half = tid & 1;
    const float4* Ap4 = (const float4*)(A + (size_t)(rowStart + r) * K + half * 16);
    const int sw = (r & 7) << 4;
    u16* aw0 = (u16*)((char*)Asm + (((r * 64 + half * 32) ^ sw)));
    u16* aw1 = (u16*)((char*)Asm + (((r * 64 + half * 32 + 16) ^ sw)));

    // B staging (swz bf16, global_load_lds)
    const int off0 = (wave * 2 + 0) * 1024 + lane * 16;
    const int off1 = (wave * 2 + 1) * 1024 + lane * 16;
    const int br0 = off0 >> 6, bk0 = (off0 & 63) >> 1;
    const int br1 = off1 >> 6, bk1 = (off1 & 63) >> 1;
    const u16* Bp0 = Bt + (size_t)(colStart + br0) * K + bk0;
    const u16* Bp1 = Bt + (size_t)(colStart + br1) * K + bk1;
    u16* Bs0 = &Bsm[(wave * 2 + 0) * 512];
    u16* Bs1 = &Bsm[(wave * 2 + 1) * 512];

    const int rsel = lane & 15, ksel = lane >> 4;
    const int fsw = ((ksel ^ (rsel & 3)) << 3);

    float4 a0, a1, a2, a3;
    {
        const float4* p = Ap4 + (k0 >> 2);
        a0 = p[0]; a1 = p[1]; a2 = p[2]; a3 = p[3];
    }
    for (int kk = k0; kk < kEnd; kk += 32) {
        gload_lds16(Bp0 + kk, Bs0);
        gload_lds16(Bp1 + kk, Bs1);
        bf16x8 c0, c1;
        c0[0] = (__bf16)a0.x; c0[1] = (__bf16)a0.y; c0[2] = (__bf16)a0.z; c0[3] = (__bf16)a0.w;
        c0[4] = (__bf16)a1.x; c0[5] = (__bf16)a1.y; c0[6] = (__bf16)a1.z; c0[7] = (__bf16)a1.w;
        c1[0] = (__bf16)a2.x; c1[1] = (__bf16)a2.y; c1[2] = (__bf16)a2.z; c1[3] = (__bf16)a2.w;
        c1[4] = (__bf16)a3.x; c1[5] = (__bf16)a3.y; c1[6] = (__bf16)a3.z; c1[7] = (__bf16)a3.w;
        *(bf16x8*)aw0 = c0;
        *(bf16x8*)aw1 = c1;
        if (kk + 32 < kEnd) {
            const float4* p = Ap4 + ((kk + 32) >> 2);
            a0 = p[0]; a1 = p[1]; a2 = p[2]; a3 = p[3];
        }
        __syncthreads();
        bf16x8 aF[4], bF[4];
#pragma unroll
        for (int mm = 0; mm < 4; ++mm) {
            int R = wr * 64 + mm * 16 + rsel;
            aF[mm] = *(const bf16x8*)((char*)Asm + ((R * 64 + ksel * 16) ^ ((R & 7) << 4)));
        }
#pragma unroll
        for (int n = 0; n < 4; ++n)
            bF[n] = *(const bf16x8*)&Bsm[(wc * 64 + n * 16 + rsel) * 32 + fsw];
#pragma unroll
        for (int mm = 0; mm < 4; ++mm)
#pragma unroll
            for (int n = 0; n < 4; ++n)
                acc[mm][n] = __builtin_amdgcn_mfma_f32_16x16x32_bf16(aF[mm], bF[n], acc[mm][n], 0, 0, 0);
        __syncthreads();
    }

    const int cq = (lane >> 4) * 4, cr = lane & 15;
#pragma unroll
    for (int mm = 0; mm < 4; ++mm)
#pragma unroll
        for (int n = 0; n < 4; ++n) {
            int col = colStart + wc * 64 + n * 16 + cr;
#pragma unroll
            for (int j = 0; j < 4; ++j) {
                int row = rowStart + wr * 64 + mm * 16 + cq + j;
                atomicAdd(&C[(size_t)row * 512 + col], acc[mm][n][j]);
            }
        }
}

// ---------------------------------------------------------------------------
// Fused per-node SDPA (4 branches, 8x8 softmax) + branch sum + RMSNorm*g2
// S12 inputs plain bf16; y output swz bf16.
// ---------------------------------------------------------------------------
struct SP12 { const u16* p[12]; };
__global__ __launch_bounds__(256) void sdpa_fused(SP12 sp, const float* __restrict__ g2,
                                                  u16* __restrict__ y) {
    __shared__ float qb[4][8][65], kb[4][8][65], vb[4][8][65];
    __shared__ float aw[4][64];
    __shared__ float red[4];
    const int n = blockIdx.x, tid = threadIdx.x;
    const size_t base = (size_t)n * 512;
    const int e0 = tid * 2, hs = e0 >> 6, ds = e0 & 63;

#pragma unroll
    for (int br = 0; br < 4; ++br) {
        unsigned u;
        u = *(const unsigned*)(sp.p[br * 3 + 0] + base + e0);
        qb[br][hs][ds] = bf2f(u & 0xffffu); qb[br][hs][ds + 1] = bf2f(u >> 16);
        u = *(const unsigned*)(sp.p[br * 3 + 1] + base + e0);
        kb[br][hs][ds] = bf2f(u & 0xffffu); kb[br][hs][ds + 1] = bf2f(u >> 16);
        u = *(const unsigned*)(sp.p[br * 3 + 2] + base + e0);
        vb[br][hs][ds] = bf2f(u & 0xffffu); vb[br][hs][ds + 1] = bf2f(u >> 16);
    }
    __syncthreads();

    const int b = tid >> 6, h = (tid >> 3) & 7, g = tid & 7;
    float s = 0.f;
    const float* qr = &qb[b][h][0];
    const float* kr = &kb[b][g][0];
#pragma unroll
    for (int j = 0; j < 64; ++j) s += qr[j] * kr[j];
    s *= 0.125f;
    float mx = s;
#pragma unroll
    for (int o = 1; o < 8; o <<= 1) mx = fmaxf(mx, __shfl_xor(mx, o));
    float p = expf(s - mx);
    float sm = p;
#pragma unroll
    for (int o = 1; o < 8; o <<= 1) sm += __shfl_xor(sm, o);
    aw[b][(h << 3) | g] = p / sm;
    __syncthreads();

    float o0 = 0.f, o1 = 0.f;
#pragma unroll
    for (int bb = 0; bb < 4; ++bb)
#pragma unroll
        for (int gg = 0; gg < 8; ++gg) {
            float a = aw[bb][(hs << 3) | gg];
            o0 += a * vb[bb][gg][ds];
            o1 += a * vb[bb][gg][ds + 1];
        }

    float ss = o0 * o0 + o1 * o1;
#pragma unroll
    for (int o = 32; o; o >>= 1) ss += __shfl_down(ss, o);
    if ((tid & 63) == 0) red[tid >> 6] = ss;
    __syncthreads();
    float tot = red[0] + red[1] + red[2] + red[3];
    float rs = rsqrtf(tot * (1.0f / 512.0f) + 1e-6f);
    unsigned pack = (unsigned)f2bf(o0 * rs * g2[e0]) | ((unsigned)f2bf(o1 * rs * g2[e0 + 1]) << 16);
    ((unsigned*)y)[(size_t)n * 256 + (tid ^ ((n & 3) << 2))] = pack;  // swz out
}

// ---------------------------------------------------------------------------
extern "C" void kernel_launch(void* const* d_in, const int* in_sizes, int n_in,
                              void* d_out, int out_size, void* d_ws, size_t ws_size,
                              hipStream_t stream) {
    (void)in_sizes; (void)n_in; (void)out_size; (void)ws_size;
    const int N = 4096, M = 16384, E = 512;

    const float* x_node = (const float*)d_in[0];
    const float* x_edge = (const float*)d_in[1];
    const float* adj    = (const float*)d_in[2];
    const float* Wp1_he = (const float*)d_in[15];
    const float* Wp1_eh = (const float*)d_in[16];
    const float* Wp1_ee = (const float*)d_in[17];
    const float* g_n = (const float*)d_in[18];
    const float* g_e = (const float*)d_in[19];
    const float* g2  = (const float*)d_in[20];
    const float* Wf1 = (const float*)d_in[21];
    const float* bf1 = (const float*)d_in[22];
    const float* Wf2 = (const float*)d_in[23];
    const float* bf2 = (const float*)d_in[24];

    // ---- workspace ----
    char* p = (char*)d_ws;
    auto alloc = [&](size_t b) { char* r = p; p += (b + 255) & ~(size_t)255; return r; };
    const size_t NP = (size_t)N * E;
    const size_t WSZ = (size_t)E * E;
    u16* h    = (u16*)alloc(NP * 2);                  // swz
    u16* e    = (u16*)alloc((size_t)M * E * 2);       // plain
    u16* eT   = (u16*)alloc((size_t)M * E * 2);       // swz (512 x 16384)
    u16* Wt   = (u16*)alloc(12 * WSZ * 2);            // swz
    u16* Wf1T = (u16*)alloc((size_t)2048 * 512 * 2);  // swz
    u16* Wf2T = (u16*)alloc((size_t)512 * 2048 * 2);  // swz
    float* F3 = (float*)alloc(3 * NP * 4);            // Pee, Peh, Phe fp32 acc
    u16* P3b  = (u16*)alloc(3 * NP * 2);              // swz
    u16* Ahb  = (u16*)alloc(NP * 2);                  // swz
    u16* S12  = (u16*)alloc(12 * NP * 2);             // plain
    u16* y    = (u16*)alloc(NP * 2);                  // swz
    u16* t    = (u16*)alloc((size_t)N * 2048 * 2);    // swz

    // ---- 1. weight transposes (swz out) ----
    W12 w12;
    for (int i = 0; i < 12; ++i) { w12.in[i] = (const float*)d_in[3 + i]; w12.out[i] = Wt + i * WSZ; }
    transpose_cvt12<<<dim3(16, 16, 12), 256, 0, stream>>>(w12);
    transpose_cvt<<<dim3(64, 16), 256, 0, stream>>>(Wf1, Wf1T, 512, 2048);
    transpose_cvt<<<dim3(16, 64), 256, 0, stream>>>(Wf2, Wf2T, 2048, 512);

    // ---- 2. RMSNorms + eT + sparse Ah ----
    rmsnorm_bf16<true><<<N, 256, 0, stream>>>(x_node, g_n, h);
    rmsnorm_bf16<false><<<M, 256, 0, stream>>>(x_edge, g_e, e);
    transpose_u16<<<dim3(16, 512), 256, 0, stream>>>(e, eT, M, 512);
    adj_spmm<<<1024, 256, 0, stream>>>(adj, h, Ahb);

    // ---- 3. big GEMMs: P = Wp1 @ e (3 batched, splitK=4) ----
    hipMemsetAsync(F3, 0, 3 * NP * 4, stream);
    Big3 bp; bp.A[0] = Wp1_ee; bp.A[1] = Wp1_eh; bp.A[2] = Wp1_he;
    gemm_f32a<<<dim3(4, 32, 12), 256, 0, stream>>>(bp, eT, F3, M, 4, 4096);
    cvt_f32_bf16<true><<<2048, 256, 0, stream>>>(F3, P3b, 3 * NP / 8);
    const u16* Peeb = P3b + 0 * NP;
    const u16* Pehb = P3b + 1 * NP;
    const u16* Pheb = P3b + 2 * NP;

    // ---- 4. 12 batched projections ----
    // S order: Qhh,Khh,Vhh, Qee,Kee,Vee, Qeh,Keh,Veh, Qhe,Khe,Vhe
    Small12 sb;
    const u16* aList[12] = {Ahb, h, h, Peeb, Peeb, h, Pehb, h, h, h, Pheb, h};
    const int wList[12]  = {0, 1, 2, 3, 4, 5, 9, 10, 11, 6, 7, 8};
    for (int i = 0; i < 12; ++i) {
        sb.A[i] = aList[i];
        sb.W[i] = Wt + wList[i] * WSZ;
        sb.C[i] = S12 + i * NP;
    }
    gemm_small12<<<dim3(4, 32, 12), 256, 0, stream>>>(sb);

    // ---- 5. SDPA + sum + RMSNorm -> y (swz) ----
    SP12 sp;
    for (int i = 0; i < 12; ++i) sp.p[i] = S12 + i * NP;
    sdpa_fused<<<N, 256, 0, stream>>>(sp, g2, y);

    // ---- 6. FFN ----
    gemm_bt<1><<<dim3(16, 32, 1), 256, 0, stream>>>(y, Wf1T, t, bf1, 2048, 512, 512);
    hipMemsetAsync(d_out, 0, NP * 4, stream);
    gemm_bt<3><<<dim3(4, 32, 2), 256, 0, stream>>>(t, Wf2T, d_out, bf2, 512, 2048, 1024);
}